// Round 19
// baseline (191.958 us; speedup 1.0000x reference)
//
#include <hip/hip_runtime.h>
#include <hip/hip_fp16.h>

#define H1 15
#define H2 81
#define FXS 10
#define FXT 5
#define FE 10
#define FU 10

#define BSH 8                 // 256 nodes per coarse bucket
#define NPB 256
#define MAXBUK 512            // supports NS up to 131072
#define PAD 16                // ints per counter slot (64B line)
#define ABLK 4096             // edges per k_mlpbin block (2x R16: 336B bursts)
#define TB1 1024              // producer threads (16 waves)
#define EPT 4                 // edges per producer thread
#define TBF 512               // fused consumer threads
#define CAPS 10240            // records per bucket cap (mean 8184 + ~22 sigma)
#define RPT 20                // CAPS / TBF

typedef _Float16 half4 __attribute__((ext_vector_type(4)));
typedef float floatx4 __attribute__((ext_vector_type(4)));
typedef unsigned int uint;
typedef unsigned short ushort;

// swizzled uint2 slot for record row/quarter (R14-proven)
__device__ __forceinline__ int sw(int row, int q) {
    return row * 8 + 2 * (q ^ ((row >> 2) & 3));
}

// ---------- bucket histogram (padded global counters) ----------
__global__ __launch_bounds__(256) void k_bhist(const int* __restrict__ src,
                                               int* __restrict__ bcnt, int E, int nbuk) {
    __shared__ int h[MAXBUK];
    for (int i = threadIdx.x; i < MAXBUK; i += 256) h[i] = 0;
    __syncthreads();
    for (int i = blockIdx.x * blockDim.x + threadIdx.x; i < E; i += gridDim.x * blockDim.x)
        atomicAdd(&h[src[i] >> BSH], 1);
    __syncthreads();
    for (int i = threadIdx.x; i < nbuk; i += 256)
        if (h[i]) atomicAdd(&bcnt[i * PAD], h[i]);
}

// ---------- bucket exclusive scan ----------
__global__ __launch_bounds__(MAXBUK) void k_bscan(const int* __restrict__ bcnt,
                                                  int* __restrict__ boffs,
                                                  int* __restrict__ bcur, int nbuk) {
    __shared__ int sc[MAXBUK];
    int t = threadIdx.x;
    int v = (t < nbuk) ? bcnt[t * PAD] : 0;
    sc[t] = v;
    __syncthreads();
    for (int d = 1; d < MAXBUK; d <<= 1) {
        int add = (t >= d) ? sc[t - d] : 0;
        __syncthreads();
        sc[t] += add;
        __syncthreads();
    }
    if (t < nbuk) { int o = sc[t] - v; boffs[t] = o; bcur[t * PAD] = o; }
}

// ---------- P1: edge-order MFMA MLP + in-place LDS binning (4096-edge tile) ----------
// record (32B): h[0..14] = fp16 edge-MLP outputs, h[15] = src_local (raw u16)
__global__ __launch_bounds__(TB1, 4) void k_mlpbin(
    const float* __restrict__ x_t, const float* __restrict__ ea,
    const float* __restrict__ W1, const float* __restrict__ b1,
    const float* __restrict__ W2, const float* __restrict__ b2,
    const int* __restrict__ src, const int* __restrict__ tgt,
    int* __restrict__ bcur, uint* __restrict__ gbin, int E)
{
    __shared__ uint stagw[ABLK * 8];          // 128 KB, swizzled records
    __shared__ int A[MAXBUK];                 // hist -> (gb - st)
    __shared__ int B[MAXBUK];                 // cursor
    __shared__ ushort sbk[ABLK];              // 8 KB
    __shared__ int wsum[8];

    int t = threadIdx.x;
    int lane = t & 63, w = t >> 6;
    int base = blockIdx.x * ABLK;
    int m = min(ABLK, E - base);

    // ---- prefetch: src/tgt for EPT edges, issued immediately ----
    int sv[EPT], tg[EPT];
    bool vv[EPT];
#pragma unroll
    for (int c = 0; c < EPT; c++) {
        int i = t + c * TB1;
        vv[c] = (i < m);
        int e = base + (vv[c] ? i : 0);
        sv[c] = src[e];
        tg[c] = tgt[e];
    }

    // ---- histogram off registers ----
    if (t < MAXBUK) A[t] = 0;
    __syncthreads();
#pragma unroll
    for (int c = 0; c < EPT; c++)
        if (vv[c]) atomicAdd(&A[sv[c] >> BSH], 1);

    // ---- issue feature gathers NOW; latency hides under scan + alloc ----
    float xt[EPT][FXT];
    float2 ev[EPT][5];
#pragma unroll
    for (int c = 0; c < EPT; c++) {
        int e = base + ((t + c * TB1 < m) ? (t + c * TB1) : 0);
        const float* xr = x_t + (size_t)tg[c] * FXT;
#pragma unroll
        for (int j = 0; j < FXT; j++) xt[c][j] = xr[j];
        const float2* er = (const float2*)(ea + (size_t)e * FE);
#pragma unroll
        for (int j = 0; j < 5; j++) ev[c][j] = er[j];
    }
    __syncthreads();

    // ---- 2-barrier shuffle scan over 512 bucket counts ----
    int h = 0, x = 0;
    if (t < MAXBUK) { h = A[t]; x = h; }
#pragma unroll
    for (int d = 1; d < 64; d <<= 1) {
        int y = __shfl_up(x, d, 64);
        if (lane >= d) x += y;
    }
    if (t < MAXBUK && lane == 63) wsum[w] = x;
    __syncthreads();
    if (w == 0) {
        int v = (lane < 8) ? wsum[lane] : 0;
        int xx = v;
#pragma unroll
        for (int d = 1; d < 8; d <<= 1) {
            int y = __shfl_up(xx, d, 64);
            if (lane >= d) xx += y;
        }
        if (lane < 8) wsum[lane] = xx - v;
    }
    __syncthreads();
    if (t < MAXBUK) {
        int st = wsum[w] + (x - h);
        B[t] = st;
        int gb = h ? atomicAdd(&bcur[t * PAD], h) : 0;
        A[t] = gb - st;                       // dst = A[bk] + bin_pos
    }
    __syncthreads();

    // ---- resident weight/bias fragments (layout HW-verified rounds 4-18) ----
    int em = lane & 15;
    int kb = (lane >> 4) << 2;
    int q = kb >> 2;
    half4 a1f, a2f;
    floatx4 c1f, c2f;
#pragma unroll
    for (int i = 0; i < 4; i++) {
        int kk = kb + i;
        bool wv = (kk < H1) && (em < H1);
        a1f[i] = wv ? (_Float16)W1[kk * H1 + em] : (_Float16)0.f;
        a2f[i] = wv ? (_Float16)W2[kk * H1 + em] : (_Float16)0.f;
        c1f[i] = (kk < H1) ? b1[kk] : 0.f;
        c2f[i] = (kk < H1) ? b2[kk] : 0.f;
    }

    // ---- stage from registers (zero global loads here) ----
#pragma unroll
    for (int c = 0; c < EPT; c++) {
        if (vv[c]) {
            int bk = sv[c] >> BSH;
            int pos = atomicAdd(&B[bk], 1);
            sbk[pos] = (ushort)bk;
            float f[15];
#pragma unroll
            for (int j = 0; j < FXT; j++) f[j] = xt[c][j];
#pragma unroll
            for (int j = 0; j < 5; j++) {
                f[FXT + 2 * j] = ev[c][j].x;
                f[FXT + 2 * j + 1] = ev[c][j].y;
            }
#pragma unroll
            for (int cc = 0; cc < 4; cc++) {
                union { _Float16 hh[4]; ushort us[4]; uint2 u; } pk;
#pragma unroll
                for (int j = 0; j < 4; j++) {
                    int fi = cc * 4 + j;
                    pk.hh[j] = (fi < 15) ? (_Float16)f[fi] : (_Float16)0.f;
                }
                if (cc == 3) pk.us[3] = (ushort)(sv[c] & (NPB - 1));
                *(uint2*)&stagw[sw(pos, cc)] = pk.u;
            }
        }
    }
    __syncthreads();

    // ---- MFMA in place: 16 waves x 256 rows = 16 groups of 16 ----
#pragma unroll
    for (int g = 0; g < ABLK / (16 * 16); g++) {
        int r = w * (ABLK / 16) + g * 16 + em;
        union { uint2 u; _Float16 hh[4]; } bin_;
        bin_.u = *(uint2*)&stagw[sw(r, q)];
        half4 bf;
#pragma unroll
        for (int j = 0; j < 4; j++) bf[j] = bin_.hh[j];
        floatx4 d1 = __builtin_amdgcn_mfma_f32_16x16x16f16(a1f, bf, c1f, 0, 0, 0);
        half4 hm;
#pragma unroll
        for (int j = 0; j < 4; j++) {
            float xx = d1[j];
            xx = fmaxf(xx, 0.1f * xx);
            hm[j] = (_Float16)xx;
        }
        floatx4 d2 = __builtin_amdgcn_mfma_f32_16x16x16f16(a2f, hm, c2f, 0, 0, 0);
        union { _Float16 hh[4]; ushort us[4]; uint uu[2]; uint2 u; } ov;
#pragma unroll
        for (int j = 0; j < 4; j++) ov.hh[j] = (_Float16)d2[j];
        uint* wp = &stagw[sw(r, q)];
        if (kb < 12) {
            *(uint2*)wp = ov.u;
        } else {
            wp[0] = ov.uu[0];
            ((ushort*)&wp[1])[0] = ov.us[2];        // preserves sid in high half
        }
    }
    __syncthreads();   // concurrent block-wide write-out merges bursts (R17 lesson)

    // ---- dense write-out: bucket-contiguous global bursts (~336B) ----
    for (int i = t; i < m; i += TB1) {
        int bk = sbk[i];
        uint2 q0 = *(uint2*)&stagw[sw(i, 0)];
        uint2 q1 = *(uint2*)&stagw[sw(i, 1)];
        uint2 q2 = *(uint2*)&stagw[sw(i, 2)];
        uint2 q3 = *(uint2*)&stagw[sw(i, 3)];
        size_t dst = (size_t)(A[bk] + i) * 8;
        *(uint4*)(gbin + dst)     = make_uint4(q0.x, q0.y, q1.x, q1.y);
        *(uint4*)(gbin + dst + 4) = make_uint4(q2.x, q2.y, q3.x, q3.y);
    }
}

// ---------- P2: fused per-bucket (256 nodes) sort-index + moments + node MLP ----------
// (verbatim R16 - verified best consumer)
__global__ __launch_bounds__(TBF, 4) void k_fuse(
    const float* __restrict__ x_s, const float* __restrict__ u,
    const float* __restrict__ W3, const float* __restrict__ b3,
    const float* __restrict__ W4, const float* __restrict__ b4,
    const int* __restrict__ batch_s,
    const int* __restrict__ bcnt, const int* __restrict__ boffs,
    const uint* __restrict__ gbin,
    float* __restrict__ out, int NSs)
{
    __shared__ ushort idx[CAPS];               // 20 KB
    __shared__ int fh[NPB], fstart[NPB], fcur[NPB];   // 3 KB
    __shared__ float sW3[H2 * FXS], sb3[FXS], sW4[FXS * FXS], sb4[FXS];
    __shared__ float feat[128][61];            // 31.2 KB (per 128-node pass)
    __shared__ float l1s[128][FXS];            // 5 KB

    int t = threadIdx.x;
    for (int i = t; i < H2 * FXS; i += TBF) sW3[i] = W3[i];
    for (int i = t; i < FXS * FXS; i += TBF) sW4[i] = W4[i];
    if (t < FXS) { sb3[t] = b3[t]; sb4[t] = b4[t]; }
    if (t < NPB) fh[t] = 0;
    __syncthreads();

    int b = blockIdx.x;
    int base = boffs[b];
    int cnt = min(bcnt[b * PAD], CAPS);
    const uint* rb = gbin + (size_t)base * 8;

    // register-staged sid pass: hist
    int sid[RPT];
#pragma unroll
    for (int c = 0; c < RPT; c++) {
        int i = t + c * TBF;
        sid[c] = -1;
        if (i < cnt) {
            sid[c] = (int)(rb[(size_t)i * 8 + 7] >> 16) & (NPB - 1);
            atomicAdd(&fh[sid[c]], 1);
        }
    }
    __syncthreads();
    if (t < NPB) fstart[t] = fh[t];
    __syncthreads();
    for (int d = 1; d < NPB; d <<= 1) {
        int add = (t < NPB && t >= d) ? fstart[t - d] : 0;
        __syncthreads();
        if (t < NPB) fstart[t] += add;
        __syncthreads();
    }
    if (t < NPB) { int s0 = fstart[t] - fh[t]; fstart[t] = s0; fcur[t] = s0; }
    __syncthreads();
    // placement from registers
#pragma unroll
    for (int c = 0; c < RPT; c++) {
        if (sid[c] >= 0) {
            int p = atomicAdd(&fcur[sid[c]], 1);
            idx[p] = (ushort)(t + c * TBF);
        }
    }
    __syncthreads();

    // ---- two 128-node passes: moments + stats + node MLP ----
    for (int pass = 0; pass < 2; pass++) {
        int l = t >> 2, lq = t & 3;            // 128 nodes x 4 lanes
        int ln = pass * 128 + l;               // local node in bucket
        int s = (b << BSH) + ln;
        int n = fh[ln], start = fstart[ln];

        float s1[4] = {0.f,0.f,0.f,0.f}, s2[4] = {0.f,0.f,0.f,0.f};
        float s3[4] = {0.f,0.f,0.f,0.f}, s4[4] = {0.f,0.f,0.f,0.f};
        if (s < NSs) {
            for (int k = 0; k < n; k++) {
                int ri = idx[start + k];
                uint2 rv = *(const uint2*)(rb + (size_t)ri * 8 + lq * 2);
                union { uint uu[2]; _Float16 h[4]; } up;
                up.uu[0] = rv.x; up.uu[1] = rv.y;
#pragma unroll
                for (int j = 0; j < 4; j++) {
                    float x = (float)up.h[j];   // f==15 slot is sid; excluded at write
                    float x2 = x * x;
                    s1[j] += x;
                    s2[j] = fmaf(x, x, s2[j]);
                    s3[j] = fmaf(x2, x, s3[j]);
                    s4[j] = fmaf(x2, x2, s4[j]);
                }
            }
            float inv = 1.0f / (float)(n > 1 ? n : 1);
#pragma unroll
            for (int j = 0; j < 4; j++) {
                int f = lq * 4 + j;
                if (f < H1) {
                    float a = s1[j] * inv, m2 = s2[j] * inv, m3 = s3[j] * inv, m4 = s4[j] * inv;
                    float a2 = a * a;
                    float var = m2 - a2;
                    float bb = sqrtf(1e-6f + fmaxf(var, 0.0f));
                    float c3 = m3 - 3.0f * a * m2 + 2.0f * a * a2;
                    float c4 = m4 - 4.0f * a * m3 + 6.0f * a2 * m2 - 3.0f * a2 * a2;
                    float ib = 1.0f / bb, ib2 = ib * ib;
                    feat[l][f * 4 + 0] = a;
                    feat[l][f * 4 + 1] = bb;
                    feat[l][f * 4 + 2] = c3 * ib * ib2;
                    feat[l][f * 4 + 3] = c4 * ib2 * ib2;
                }
            }
            if (lq == 0) feat[l][60] = (float)n;
        }
        __syncthreads();

        // node MLP layer 1 (epilogue pattern verified R10)
        for (int id = t; id < 128 * FXS; id += TBF) {
            int g = id / FXS, j = id - g * FXS;
            int ss = (b << BSH) + pass * 128 + g;
            if (ss >= NSs) continue;
            const float* ar = feat[g];
            float acc = sb3[j];
            const float* xr = x_s + (size_t)ss * FXS;
#pragma unroll
            for (int i = 0; i < FXS; i++) acc = fmaf(xr[i], sW3[i * FXS + j], acc);
            acc = fmaf(ar[60], sW3[FXS * FXS + j], acc);
#pragma unroll
            for (int f = 0; f < H1; f++) {
                acc = fmaf(ar[f * 4 + 0], sW3[(11 + f) * FXS + j], acc);
                acc = fmaf(ar[f * 4 + 1], sW3[(26 + f) * FXS + j], acc);
                acc = fmaf(ar[f * 4 + 2], sW3[(41 + f) * FXS + j], acc);
                acc = fmaf(ar[f * 4 + 3], sW3[(56 + f) * FXS + j], acc);
            }
            const float* ur = u + (size_t)batch_s[ss] * FU;
#pragma unroll
            for (int i = 0; i < FU; i++) acc = fmaf(ur[i], sW3[(71 + i) * FXS + j], acc);
            l1s[g][j] = fmaxf(acc, 0.1f * acc);
        }
        __syncthreads();

        // node MLP layer 2 + output
        for (int id = t; id < 128 * FXS; id += TBF) {
            int g = id / FXS, j = id - g * FXS;
            int ss = (b << BSH) + pass * 128 + g;
            if (ss >= NSs) continue;
            float acc = sb4[j];
#pragma unroll
            for (int i = 0; i < FXS; i++) acc = fmaf(l1s[g][i], sW4[i * FXS + j], acc);
            out[(size_t)ss * FXS + j] = acc;
        }
        __syncthreads();   // feat/l1s reused next pass
    }
}

extern "C" void kernel_launch(void* const* d_in, const int* in_sizes, int n_in,
                              void* d_out, int out_size, void* d_ws, size_t ws_size,
                              hipStream_t stream) {
    const float* x_s = (const float*)d_in[0];
    const float* x_t = (const float*)d_in[1];
    const float* ea  = (const float*)d_in[2];
    const float* u   = (const float*)d_in[3];
    const float* W1  = (const float*)d_in[4];
    const float* b1  = (const float*)d_in[5];
    const float* W2  = (const float*)d_in[6];
    const float* b2  = (const float*)d_in[7];
    const float* W3  = (const float*)d_in[8];
    const float* b3  = (const float*)d_in[9];
    const float* W4  = (const float*)d_in[10];
    const float* b4  = (const float*)d_in[11];
    const int* src   = (const int*)d_in[12];
    const int* tgt   = (const int*)d_in[13];
    const int* batch_s = (const int*)d_in[14];

    int NSs = in_sizes[0] / FXS;
    int E   = in_sizes[2] / FE;
    int nbuk = (NSs + NPB - 1) >> BSH;

    auto align_up = [](size_t x) { return (x + 255) & ~(size_t)255; };
    char* w = (char*)d_ws;
    int* bcnt   = (int*)w; w += align_up((size_t)MAXBUK * PAD * 4);
    int* boffs  = (int*)w; w += align_up((size_t)MAXBUK * 4);
    int* bcur   = (int*)w; w += align_up((size_t)MAXBUK * PAD * 4);
    uint* gbin  = (uint*)w;   // E * 32 bytes

    hipMemsetAsync(bcnt, 0, (size_t)MAXBUK * PAD * 4, stream);

    k_bhist<<<512, 256, 0, stream>>>(src, bcnt, E, nbuk);
    k_bscan<<<1, MAXBUK, 0, stream>>>(bcnt, boffs, bcur, nbuk);
    k_mlpbin<<<(E + ABLK - 1) / ABLK, TB1, 0, stream>>>(
        x_t, ea, W1, b1, W2, b2, src, tgt, bcur, gbin, E);
    k_fuse<<<nbuk, TBF, 0, stream>>>(
        x_s, u, W3, b3, W4, b4, batch_s, bcnt, boffs, gbin, (float*)d_out, NSs);
}

// Round 20
// 184.940 us; speedup vs baseline: 1.0379x; 1.0379x over previous
//
#include <hip/hip_runtime.h>
#include <hip/hip_fp16.h>

#define H1 15
#define H2 81
#define FXS 10
#define FXT 5
#define FE 10
#define FU 10

#define BSH 9                 // 512 nodes per coarse bucket
#define NPB 512
#define MAXBUK 256            // supports NS up to 131072
#define PAD 16                // ints per counter slot (64B line)
#define ABLK 2048             // edges per k_mlpbin block (R16 LDS/occupancy)
#define TB1 1024              // producer threads (16 waves)
#define TBF 1024              // fused consumer threads (16 waves, 1 block/CU)
#define CAPS 18432            // records per bucket cap (mean 16384 + 16 sigma)
#define RPT 18                // CAPS / TBF

typedef _Float16 half4 __attribute__((ext_vector_type(4)));
typedef float floatx4 __attribute__((ext_vector_type(4)));
typedef unsigned int uint;
typedef unsigned short ushort;

// swizzled uint2 slot for record row/quarter (R14-proven)
__device__ __forceinline__ int sw(int row, int q) {
    return row * 8 + 2 * (q ^ ((row >> 2) & 3));
}

// ---------- bucket histogram (padded global counters) ----------
__global__ __launch_bounds__(256) void k_bhist(const int* __restrict__ src,
                                               int* __restrict__ bcnt, int E, int nbuk) {
    __shared__ int h[MAXBUK];
    for (int i = threadIdx.x; i < MAXBUK; i += 256) h[i] = 0;
    __syncthreads();
    for (int i = blockIdx.x * blockDim.x + threadIdx.x; i < E; i += gridDim.x * blockDim.x)
        atomicAdd(&h[src[i] >> BSH], 1);
    __syncthreads();
    for (int i = threadIdx.x; i < nbuk; i += 256)
        if (h[i]) atomicAdd(&bcnt[i * PAD], h[i]);
}

// ---------- bucket exclusive scan (256 entries, 1 block) ----------
__global__ __launch_bounds__(MAXBUK) void k_bscan(const int* __restrict__ bcnt,
                                                  int* __restrict__ boffs,
                                                  int* __restrict__ bcur, int nbuk) {
    __shared__ int sc[MAXBUK];
    int t = threadIdx.x;
    int v = (t < nbuk) ? bcnt[t * PAD] : 0;
    sc[t] = v;
    __syncthreads();
    for (int d = 1; d < MAXBUK; d <<= 1) {
        int add = (t >= d) ? sc[t - d] : 0;
        __syncthreads();
        sc[t] += add;
        __syncthreads();
    }
    if (t < nbuk) { int o = sc[t] - v; boffs[t] = o; bcur[t * PAD] = o; }
}

// ---------- P1: edge-order MFMA MLP + in-place LDS binning (R16 structure, BSH=9) ----------
// record (32B): h[0..14] = fp16 edge-MLP outputs, h[15] = src_local (raw u16, 0..511)
__global__ __launch_bounds__(TB1, 8) void k_mlpbin(
    const float* __restrict__ x_t, const float* __restrict__ ea,
    const float* __restrict__ W1, const float* __restrict__ b1,
    const float* __restrict__ W2, const float* __restrict__ b2,
    const int* __restrict__ src, const int* __restrict__ tgt,
    int* __restrict__ bcur, uint* __restrict__ gbin, int E)
{
    __shared__ uint stagw[ABLK * 8];          // 64 KB, swizzled records
    __shared__ int A[MAXBUK];                 // hist -> (gb - st)
    __shared__ int B[MAXBUK];                 // cursor
    __shared__ ushort sbk[ABLK];              // 4 KB
    __shared__ int wsum[4];

    int t = threadIdx.x;
    int lane = t & 63, w = t >> 6;
    int base = blockIdx.x * ABLK;
    int m = min(ABLK, E - base);

    // ---- prefetch: src/tgt for both edges, issued immediately ----
    int i0 = t, i1 = t + TB1;
    bool v0 = (i0 < m), v1 = (i1 < m);
    int e0 = base + (v0 ? i0 : 0);
    int e1 = base + (v1 ? i1 : 0);
    int sv0 = src[e0], tg0 = tgt[e0];
    int sv1 = src[e1], tg1 = tgt[e1];

    // ---- histogram off registers ----
    if (t < MAXBUK) A[t] = 0;
    __syncthreads();
    if (v0) atomicAdd(&A[sv0 >> BSH], 1);
    if (v1) atomicAdd(&A[sv1 >> BSH], 1);

    // ---- issue feature gathers NOW; latency hides under scan + alloc ----
    float xt0[FXT], xt1[FXT];
    float2 ev0[5], ev1[5];
    {
        const float* xr0 = x_t + (size_t)tg0 * FXT;
        const float* xr1 = x_t + (size_t)tg1 * FXT;
#pragma unroll
        for (int j = 0; j < FXT; j++) { xt0[j] = xr0[j]; xt1[j] = xr1[j]; }
        const float2* er0 = (const float2*)(ea + (size_t)e0 * FE);
        const float2* er1 = (const float2*)(ea + (size_t)e1 * FE);
#pragma unroll
        for (int j = 0; j < 5; j++) { ev0[j] = er0[j]; ev1[j] = er1[j]; }
    }
    __syncthreads();

    // ---- 2-barrier shuffle scan over 256 bucket counts (4 waves active) ----
    int h = 0, x = 0;
    if (t < MAXBUK) { h = A[t]; x = h; }
#pragma unroll
    for (int d = 1; d < 64; d <<= 1) {
        int y = __shfl_up(x, d, 64);
        if (lane >= d) x += y;
    }
    if (t < MAXBUK && lane == 63) wsum[w] = x;
    __syncthreads();
    if (w == 0) {
        int v = (lane < 4) ? wsum[lane] : 0;
        int xx = v;
#pragma unroll
        for (int d = 1; d < 4; d <<= 1) {
            int y = __shfl_up(xx, d, 64);
            if (lane >= d) xx += y;
        }
        if (lane < 4) wsum[lane] = xx - v;
    }
    __syncthreads();
    if (t < MAXBUK) {
        int st = wsum[w] + (x - h);
        B[t] = st;
        int gb = h ? atomicAdd(&bcur[t * PAD], h) : 0;
        A[t] = gb - st;                       // dst = A[bk] + bin_pos
    }
    __syncthreads();

    // ---- resident weight/bias fragments (layout HW-verified rounds 4-19) ----
    int em = lane & 15;
    int kb = (lane >> 4) << 2;
    int q = kb >> 2;
    half4 a1f, a2f;
    floatx4 c1f, c2f;
#pragma unroll
    for (int i = 0; i < 4; i++) {
        int kk = kb + i;
        bool wv = (kk < H1) && (em < H1);
        a1f[i] = wv ? (_Float16)W1[kk * H1 + em] : (_Float16)0.f;
        a2f[i] = wv ? (_Float16)W2[kk * H1 + em] : (_Float16)0.f;
        c1f[i] = (kk < H1) ? b1[kk] : 0.f;
        c2f[i] = (kk < H1) ? b2[kk] : 0.f;
    }

    // ---- stage from registers (zero global loads here) ----
#define STAGE_EDGE(sv, xt, ev)                                                  \
    {                                                                           \
        int bk = (sv) >> BSH;                                                   \
        int pos = atomicAdd(&B[bk], 1);                                         \
        sbk[pos] = (ushort)bk;                                                  \
        float f[15];                                                            \
        _Pragma("unroll")                                                       \
        for (int j = 0; j < FXT; j++) f[j] = (xt)[j];                           \
        _Pragma("unroll")                                                       \
        for (int j = 0; j < 5; j++) {                                           \
            f[FXT + 2 * j] = (ev)[j].x;                                         \
            f[FXT + 2 * j + 1] = (ev)[j].y;                                     \
        }                                                                       \
        _Pragma("unroll")                                                       \
        for (int c = 0; c < 4; c++) {                                           \
            union { _Float16 hh[4]; ushort us[4]; uint2 u; } pk;                \
            _Pragma("unroll")                                                   \
            for (int j = 0; j < 4; j++) {                                       \
                int fi = c * 4 + j;                                             \
                pk.hh[j] = (fi < 15) ? (_Float16)f[fi] : (_Float16)0.f;         \
            }                                                                   \
            if (c == 3) pk.us[3] = (ushort)((sv) & (NPB - 1));                  \
            *(uint2*)&stagw[sw(pos, c)] = pk.u;                                 \
        }                                                                       \
    }
    if (v0) STAGE_EDGE(sv0, xt0, ev0)
    if (v1) STAGE_EDGE(sv1, xt1, ev1)
#undef STAGE_EDGE
    __syncthreads();

    // ---- MFMA in place: 16 waves x 128 rows ----
#pragma unroll
    for (int g = 0; g < ABLK / (16 * 16); g++) {
        int r = w * 128 + g * 16 + em;
        union { uint2 u; _Float16 hh[4]; } bin_;
        bin_.u = *(uint2*)&stagw[sw(r, q)];
        half4 bf;
#pragma unroll
        for (int j = 0; j < 4; j++) bf[j] = bin_.hh[j];
        floatx4 d1 = __builtin_amdgcn_mfma_f32_16x16x16f16(a1f, bf, c1f, 0, 0, 0);
        half4 hm;
#pragma unroll
        for (int j = 0; j < 4; j++) {
            float xx = d1[j];
            xx = fmaxf(xx, 0.1f * xx);
            hm[j] = (_Float16)xx;
        }
        floatx4 d2 = __builtin_amdgcn_mfma_f32_16x16x16f16(a2f, hm, c2f, 0, 0, 0);
        union { _Float16 hh[4]; ushort us[4]; uint uu[2]; uint2 u; } ov;
#pragma unroll
        for (int j = 0; j < 4; j++) ov.hh[j] = (_Float16)d2[j];
        uint* wp = &stagw[sw(r, q)];
        if (kb < 12) {
            *(uint2*)wp = ov.u;
        } else {
            wp[0] = ov.uu[0];
            ((ushort*)&wp[1])[0] = ov.us[2];        // preserves sid in high half
        }
    }
    __syncthreads();   // concurrent block-wide write-out merges bursts (R17 lesson)

    // ---- dense write-out: bucket-contiguous global bursts (~336B) ----
    for (int i = t; i < m; i += TB1) {
        int bk = sbk[i];
        uint2 q0 = *(uint2*)&stagw[sw(i, 0)];
        uint2 q1 = *(uint2*)&stagw[sw(i, 1)];
        uint2 q2 = *(uint2*)&stagw[sw(i, 2)];
        uint2 q3 = *(uint2*)&stagw[sw(i, 3)];
        size_t dst = (size_t)(A[bk] + i) * 8;
        *(uint4*)(gbin + dst)     = make_uint4(q0.x, q0.y, q1.x, q1.y);
        *(uint4*)(gbin + dst + 4) = make_uint4(q2.x, q2.y, q3.x, q3.y);
    }
}

// ---------- P2: fused per-bucket (512 nodes) sort-index + moments + node MLP ----------
// TBF=1024, 1 block/CU x 16 waves (same wave count as R16's 2x8).
// Two 256-node passes over the shared idx list.
__global__ __launch_bounds__(TBF, 1) void k_fuse(
    const float* __restrict__ x_s, const float* __restrict__ u,
    const float* __restrict__ W3, const float* __restrict__ b3,
    const float* __restrict__ W4, const float* __restrict__ b4,
    const int* __restrict__ batch_s,
    const int* __restrict__ bcnt, const int* __restrict__ boffs,
    const uint* __restrict__ gbin,
    float* __restrict__ out, int NSs)
{
    __shared__ ushort idx[CAPS];               // 36 KB
    __shared__ int fh[NPB], fstart[NPB], fcur[NPB];   // 6 KB
    __shared__ float sW3[H2 * FXS], sb3[FXS], sW4[FXS * FXS], sb4[FXS];
    __shared__ float feat[256][61];            // 62.5 KB (per 256-node pass)
    __shared__ float l1s[256][FXS];            // 10 KB

    int t = threadIdx.x;
    for (int i = t; i < H2 * FXS; i += TBF) sW3[i] = W3[i];
    for (int i = t; i < FXS * FXS; i += TBF) sW4[i] = W4[i];
    if (t < FXS) { sb3[t] = b3[t]; sb4[t] = b4[t]; }
    if (t < NPB) fh[t] = 0;
    __syncthreads();

    int b = blockIdx.x;
    int base = boffs[b];
    int cnt = min(bcnt[b * PAD], CAPS);
    const uint* rb = gbin + (size_t)base * 8;

    // register-staged sid pass: hist
    int sid[RPT];
#pragma unroll
    for (int c = 0; c < RPT; c++) {
        int i = t + c * TBF;
        sid[c] = -1;
        if (i < cnt) {
            sid[c] = (int)(rb[(size_t)i * 8 + 7] >> 16) & (NPB - 1);
            atomicAdd(&fh[sid[c]], 1);
        }
    }
    __syncthreads();
    if (t < NPB) fstart[t] = fh[t];
    __syncthreads();
    for (int d = 1; d < NPB; d <<= 1) {
        int add = (t < NPB && t >= d) ? fstart[t - d] : 0;
        __syncthreads();
        if (t < NPB) fstart[t] += add;
        __syncthreads();
    }
    if (t < NPB) { int s0 = fstart[t] - fh[t]; fstart[t] = s0; fcur[t] = s0; }
    __syncthreads();
    // placement from registers
#pragma unroll
    for (int c = 0; c < RPT; c++) {
        if (sid[c] >= 0) {
            int p = atomicAdd(&fcur[sid[c]], 1);
            idx[p] = (ushort)(t + c * TBF);
        }
    }
    __syncthreads();

    // ---- two 256-node passes: moments + stats + node MLP ----
    for (int pass = 0; pass < 2; pass++) {
        int l = t >> 2, lq = t & 3;            // 256 nodes x 4 lanes
        int ln = pass * 256 + l;               // local node in bucket
        int s = (b << BSH) + ln;
        int n = fh[ln], start = fstart[ln];

        float s1[4] = {0.f,0.f,0.f,0.f}, s2[4] = {0.f,0.f,0.f,0.f};
        float s3[4] = {0.f,0.f,0.f,0.f}, s4[4] = {0.f,0.f,0.f,0.f};
        if (s < NSs) {
            for (int k = 0; k < n; k++) {
                int ri = idx[start + k];
                uint2 rv = *(const uint2*)(rb + (size_t)ri * 8 + lq * 2);
                union { uint uu[2]; _Float16 h[4]; } up;
                up.uu[0] = rv.x; up.uu[1] = rv.y;
#pragma unroll
                for (int j = 0; j < 4; j++) {
                    float x = (float)up.h[j];   // f==15 slot is sid; excluded at write
                    float x2 = x * x;
                    s1[j] += x;
                    s2[j] = fmaf(x, x, s2[j]);
                    s3[j] = fmaf(x2, x, s3[j]);
                    s4[j] = fmaf(x2, x2, s4[j]);
                }
            }
            float inv = 1.0f / (float)(n > 1 ? n : 1);
#pragma unroll
            for (int j = 0; j < 4; j++) {
                int f = lq * 4 + j;
                if (f < H1) {
                    float a = s1[j] * inv, m2 = s2[j] * inv, m3 = s3[j] * inv, m4 = s4[j] * inv;
                    float a2 = a * a;
                    float var = m2 - a2;
                    float bb = sqrtf(1e-6f + fmaxf(var, 0.0f));
                    float c3 = m3 - 3.0f * a * m2 + 2.0f * a * a2;
                    float c4 = m4 - 4.0f * a * m3 + 6.0f * a2 * m2 - 3.0f * a2 * a2;
                    float ib = 1.0f / bb, ib2 = ib * ib;
                    feat[l][f * 4 + 0] = a;
                    feat[l][f * 4 + 1] = bb;
                    feat[l][f * 4 + 2] = c3 * ib * ib2;
                    feat[l][f * 4 + 3] = c4 * ib2 * ib2;
                }
            }
            if (lq == 0) feat[l][60] = (float)n;
        }
        __syncthreads();

        // node MLP layer 1 (epilogue pattern verified R10)
        for (int id = t; id < 256 * FXS; id += TBF) {
            int g = id / FXS, j = id - g * FXS;
            int ss = (b << BSH) + pass * 256 + g;
            if (ss >= NSs) continue;
            const float* ar = feat[g];
            float acc = sb3[j];
            const float* xr = x_s + (size_t)ss * FXS;
#pragma unroll
            for (int i = 0; i < FXS; i++) acc = fmaf(xr[i], sW3[i * FXS + j], acc);
            acc = fmaf(ar[60], sW3[FXS * FXS + j], acc);
#pragma unroll
            for (int f = 0; f < H1; f++) {
                acc = fmaf(ar[f * 4 + 0], sW3[(11 + f) * FXS + j], acc);
                acc = fmaf(ar[f * 4 + 1], sW3[(26 + f) * FXS + j], acc);
                acc = fmaf(ar[f * 4 + 2], sW3[(41 + f) * FXS + j], acc);
                acc = fmaf(ar[f * 4 + 3], sW3[(56 + f) * FXS + j], acc);
            }
            const float* ur = u + (size_t)batch_s[ss] * FU;
#pragma unroll
            for (int i = 0; i < FU; i++) acc = fmaf(ur[i], sW3[(71 + i) * FXS + j], acc);
            l1s[g][j] = fmaxf(acc, 0.1f * acc);
        }
        __syncthreads();

        // node MLP layer 2 + output
        for (int id = t; id < 256 * FXS; id += TBF) {
            int g = id / FXS, j = id - g * FXS;
            int ss = (b << BSH) + pass * 256 + g;
            if (ss >= NSs) continue;
            float acc = sb4[j];
#pragma unroll
            for (int i = 0; i < FXS; i++) acc = fmaf(l1s[g][i], sW4[i * FXS + j], acc);
            out[(size_t)ss * FXS + j] = acc;
        }
        __syncthreads();   // feat/l1s reused next pass
    }
}

extern "C" void kernel_launch(void* const* d_in, const int* in_sizes, int n_in,
                              void* d_out, int out_size, void* d_ws, size_t ws_size,
                              hipStream_t stream) {
    const float* x_s = (const float*)d_in[0];
    const float* x_t = (const float*)d_in[1];
    const float* ea  = (const float*)d_in[2];
    const float* u   = (const float*)d_in[3];
    const float* W1  = (const float*)d_in[4];
    const float* b1  = (const float*)d_in[5];
    const float* W2  = (const float*)d_in[6];
    const float* b2  = (const float*)d_in[7];
    const float* W3  = (const float*)d_in[8];
    const float* b3  = (const float*)d_in[9];
    const float* W4  = (const float*)d_in[10];
    const float* b4  = (const float*)d_in[11];
    const int* src   = (const int*)d_in[12];
    const int* tgt   = (const int*)d_in[13];
    const int* batch_s = (const int*)d_in[14];

    int NSs = in_sizes[0] / FXS;
    int E   = in_sizes[2] / FE;
    int nbuk = (NSs + NPB - 1) >> BSH;

    auto align_up = [](size_t x) { return (x + 255) & ~(size_t)255; };
    char* w = (char*)d_ws;
    int* bcnt   = (int*)w; w += align_up((size_t)MAXBUK * PAD * 4);
    int* boffs  = (int*)w; w += align_up((size_t)MAXBUK * 4);
    int* bcur   = (int*)w; w += align_up((size_t)MAXBUK * PAD * 4);
    uint* gbin  = (uint*)w;   // E * 32 bytes

    hipMemsetAsync(bcnt, 0, (size_t)MAXBUK * PAD * 4, stream);

    k_bhist<<<512, 256, 0, stream>>>(src, bcnt, E, nbuk);
    k_bscan<<<1, MAXBUK, 0, stream>>>(bcnt, boffs, bcur, nbuk);
    k_mlpbin<<<(E + ABLK - 1) / ABLK, TB1, 0, stream>>>(
        x_t, ea, W1, b1, W2, b2, src, tgt, bcur, gbin, E);
    k_fuse<<<nbuk, TBF, 0, stream>>>(
        x_s, u, W3, b3, W4, b4, batch_s, bcnt, boffs, gbin, (float*)d_out, NSs);
}

// Round 21
// 173.201 us; speedup vs baseline: 1.1083x; 1.0678x over previous
//
#include <hip/hip_runtime.h>
#include <hip/hip_fp16.h>

#define H1 15
#define H2 81
#define FXS 10
#define FXT 5
#define FE 10
#define FU 10

#define BSH 8                 // 256 nodes per coarse bucket
#define NPB 256
#define MAXBUK 512            // supports NS up to 131072
#define ABLK 2048             // edges per k_mlpbin block
#define TB1 1024              // producer threads (16 waves)
#define TBF 512               // fused consumer threads
#define CAPS 10240            // records per bucket cap (mean 8184 + ~22 sigma)
#define RPT 20                // CAPS / TBF

typedef _Float16 half4 __attribute__((ext_vector_type(4)));
typedef float floatx4 __attribute__((ext_vector_type(4)));
typedef unsigned int uint;
typedef unsigned short ushort;

// swizzled uint2 slot for record row/quarter (R14-proven)
__device__ __forceinline__ int sw(int row, int q) {
    return row * 8 + 2 * (q ^ ((row >> 2) & 3));
}

// ---------- bucket histogram ----------
__global__ __launch_bounds__(256) void k_bhist(const int* __restrict__ src,
                                               int* __restrict__ bcnt, int E, int nbuk) {
    __shared__ int h[MAXBUK];
    for (int i = threadIdx.x; i < MAXBUK; i += 256) h[i] = 0;
    __syncthreads();
    for (int i = blockIdx.x * blockDim.x + threadIdx.x; i < E; i += gridDim.x * blockDim.x)
        atomicAdd(&h[src[i] >> BSH], 1);
    __syncthreads();
    for (int i = threadIdx.x; i < nbuk; i += 256)
        if (h[i]) atomicAdd(&bcnt[i], h[i]);
}

// ---------- bucket exclusive scan ----------
__global__ __launch_bounds__(MAXBUK) void k_bscan(const int* __restrict__ bcnt,
                                                  int* __restrict__ boffs,
                                                  int* __restrict__ bcur, int nbuk) {
    __shared__ int sc[MAXBUK];
    int t = threadIdx.x;
    int v = (t < nbuk) ? bcnt[t] : 0;
    sc[t] = v;
    __syncthreads();
    for (int d = 1; d < MAXBUK; d <<= 1) {
        int add = (t >= d) ? sc[t - d] : 0;
        __syncthreads();
        sc[t] += add;
        __syncthreads();
    }
    if (t < nbuk) { int o = sc[t] - v; boffs[t] = o; bcur[t] = o; }
}

// ---------- P1: edge-order MFMA MLP + in-place LDS binning, prefetched ----------
// record (32B): h[0..14] = fp16 edge-MLP outputs, h[15] = src_local (raw u16)
__global__ __launch_bounds__(TB1, 8) void k_mlpbin(
    const float* __restrict__ x_t, const float* __restrict__ ea,
    const float* __restrict__ W1, const float* __restrict__ b1,
    const float* __restrict__ W2, const float* __restrict__ b2,
    const int* __restrict__ src, const int* __restrict__ tgt,
    int* __restrict__ bcur, uint* __restrict__ gbin, int E)
{
    __shared__ uint stagw[ABLK * 8];          // 64 KB, swizzled records
    __shared__ int A[MAXBUK];                 // hist -> (gb - st)
    __shared__ int B[MAXBUK];                 // cursor
    __shared__ ushort sbk[ABLK];              // 4 KB
    __shared__ int wsum[8];

    int t = threadIdx.x;
    int lane = t & 63, w = t >> 6;
    int base = blockIdx.x * ABLK;
    int m = min(ABLK, E - base);

    // ---- prefetch: src/tgt for both edges, issued immediately ----
    int i0 = t, i1 = t + TB1;
    bool v0 = (i0 < m), v1 = (i1 < m);
    int e0 = base + (v0 ? i0 : 0);
    int e1 = base + (v1 ? i1 : 0);
    int sv0 = src[e0], tg0 = tgt[e0];
    int sv1 = src[e1], tg1 = tgt[e1];

    // ---- histogram off registers ----
    if (t < MAXBUK) A[t] = 0;
    __syncthreads();
    if (v0) atomicAdd(&A[sv0 >> BSH], 1);
    if (v1) atomicAdd(&A[sv1 >> BSH], 1);

    // ---- issue feature gathers NOW; latency hides under scan + alloc ----
    float xt0[FXT], xt1[FXT];
    float2 ev0[5], ev1[5];
    {
        const float* xr0 = x_t + (size_t)tg0 * FXT;
        const float* xr1 = x_t + (size_t)tg1 * FXT;
#pragma unroll
        for (int j = 0; j < FXT; j++) { xt0[j] = xr0[j]; xt1[j] = xr1[j]; }
        const float2* er0 = (const float2*)(ea + (size_t)e0 * FE);
        const float2* er1 = (const float2*)(ea + (size_t)e1 * FE);
#pragma unroll
        for (int j = 0; j < 5; j++) { ev0[j] = er0[j]; ev1[j] = er1[j]; }
    }
    __syncthreads();

    // ---- 2-barrier shuffle scan over 512 bucket counts ----
    int h = 0, x = 0;
    if (t < MAXBUK) { h = A[t]; x = h; }
#pragma unroll
    for (int d = 1; d < 64; d <<= 1) {
        int y = __shfl_up(x, d, 64);
        if (lane >= d) x += y;
    }
    if (t < MAXBUK && lane == 63) wsum[w] = x;
    __syncthreads();
    if (w == 0) {
        int v = (lane < 8) ? wsum[lane] : 0;
        int xx = v;
#pragma unroll
        for (int d = 1; d < 8; d <<= 1) {
            int y = __shfl_up(xx, d, 64);
            if (lane >= d) xx += y;
        }
        if (lane < 8) wsum[lane] = xx - v;
    }
    __syncthreads();
    if (t < MAXBUK) {
        int st = wsum[w] + (x - h);
        B[t] = st;
        int gb = h ? atomicAdd(&bcur[t], h) : 0;
        A[t] = gb - st;                       // dst = A[bk] + bin_pos
    }
    __syncthreads();

    // ---- resident weight/bias fragments (layout HW-verified rounds 4-20) ----
    int em = lane & 15;
    int kb = (lane >> 4) << 2;
    int q = kb >> 2;
    half4 a1f, a2f;
    floatx4 c1f, c2f;
#pragma unroll
    for (int i = 0; i < 4; i++) {
        int kk = kb + i;
        bool wv = (kk < H1) && (em < H1);
        a1f[i] = wv ? (_Float16)W1[kk * H1 + em] : (_Float16)0.f;
        a2f[i] = wv ? (_Float16)W2[kk * H1 + em] : (_Float16)0.f;
        c1f[i] = (kk < H1) ? b1[kk] : 0.f;
        c2f[i] = (kk < H1) ? b2[kk] : 0.f;
    }

    // ---- stage from registers (zero global loads here) ----
#define STAGE_EDGE(sv, xt, ev)                                                  \
    {                                                                           \
        int bk = (sv) >> BSH;                                                   \
        int pos = atomicAdd(&B[bk], 1);                                         \
        sbk[pos] = (ushort)bk;                                                  \
        float f[15];                                                            \
        _Pragma("unroll")                                                       \
        for (int j = 0; j < FXT; j++) f[j] = (xt)[j];                           \
        _Pragma("unroll")                                                       \
        for (int j = 0; j < 5; j++) {                                           \
            f[FXT + 2 * j] = (ev)[j].x;                                         \
            f[FXT + 2 * j + 1] = (ev)[j].y;                                     \
        }                                                                       \
        _Pragma("unroll")                                                       \
        for (int c = 0; c < 4; c++) {                                           \
            union { _Float16 hh[4]; ushort us[4]; uint2 u; } pk;                \
            _Pragma("unroll")                                                   \
            for (int j = 0; j < 4; j++) {                                       \
                int fi = c * 4 + j;                                             \
                pk.hh[j] = (fi < 15) ? (_Float16)f[fi] : (_Float16)0.f;         \
            }                                                                   \
            if (c == 3) pk.us[3] = (ushort)((sv) & (NPB - 1));                  \
            *(uint2*)&stagw[sw(pos, c)] = pk.u;                                 \
        }                                                                       \
    }
    if (v0) STAGE_EDGE(sv0, xt0, ev0)
    if (v1) STAGE_EDGE(sv1, xt1, ev1)
#undef STAGE_EDGE
    __syncthreads();

    // ---- MFMA in place: 16 waves x 128 rows ----
#pragma unroll
    for (int g = 0; g < ABLK / (16 * 16); g++) {
        int r = w * 128 + g * 16 + em;
        union { uint2 u; _Float16 hh[4]; } bin_;
        bin_.u = *(uint2*)&stagw[sw(r, q)];
        half4 bf;
#pragma unroll
        for (int j = 0; j < 4; j++) bf[j] = bin_.hh[j];
        floatx4 d1 = __builtin_amdgcn_mfma_f32_16x16x16f16(a1f, bf, c1f, 0, 0, 0);
        half4 hm;
#pragma unroll
        for (int j = 0; j < 4; j++) {
            float xx = d1[j];
            xx = fmaxf(xx, 0.1f * xx);
            hm[j] = (_Float16)xx;
        }
        floatx4 d2 = __builtin_amdgcn_mfma_f32_16x16x16f16(a2f, hm, c2f, 0, 0, 0);
        union { _Float16 hh[4]; ushort us[4]; uint uu[2]; uint2 u; } ov;
#pragma unroll
        for (int j = 0; j < 4; j++) ov.hh[j] = (_Float16)d2[j];
        uint* wp = &stagw[sw(r, q)];
        if (kb < 12) {
            *(uint2*)wp = ov.u;
        } else {
            wp[0] = ov.uu[0];
            ((ushort*)&wp[1])[0] = ov.us[2];        // preserves sid in high half
        }
    }
    __syncthreads();   // concurrent block-wide write-out merges bursts (R17 lesson)

    // ---- dense write-out: bucket-contiguous global bursts (~168B) ----
    for (int i = t; i < m; i += TB1) {
        int bk = sbk[i];
        uint2 q0 = *(uint2*)&stagw[sw(i, 0)];
        uint2 q1 = *(uint2*)&stagw[sw(i, 1)];
        uint2 q2 = *(uint2*)&stagw[sw(i, 2)];
        uint2 q3 = *(uint2*)&stagw[sw(i, 3)];
        size_t dst = (size_t)(A[bk] + i) * 8;
        *(uint4*)(gbin + dst)     = make_uint4(q0.x, q0.y, q1.x, q1.y);
        *(uint4*)(gbin + dst + 4) = make_uint4(q2.x, q2.y, q3.x, q3.y);
    }
}

// ---------- P2: fused per-bucket (256 nodes) sort-index + moments + node MLP ----------
__global__ __launch_bounds__(TBF, 4) void k_fuse(
    const float* __restrict__ x_s, const float* __restrict__ u,
    const float* __restrict__ W3, const float* __restrict__ b3,
    const float* __restrict__ W4, const float* __restrict__ b4,
    const int* __restrict__ batch_s,
    const int* __restrict__ bcnt, const int* __restrict__ boffs,
    const uint* __restrict__ gbin,
    float* __restrict__ out, int NSs)
{
    __shared__ ushort idx[CAPS];               // 20 KB
    __shared__ int fh[NPB], fstart[NPB], fcur[NPB];   // 3 KB
    __shared__ float sW3[H2 * FXS], sb3[FXS], sW4[FXS * FXS], sb4[FXS];
    __shared__ float feat[128][61];            // 31.2 KB (per 128-node pass)
    __shared__ float l1s[128][FXS];            // 5 KB

    int t = threadIdx.x;
    for (int i = t; i < H2 * FXS; i += TBF) sW3[i] = W3[i];
    for (int i = t; i < FXS * FXS; i += TBF) sW4[i] = W4[i];
    if (t < FXS) { sb3[t] = b3[t]; sb4[t] = b4[t]; }
    if (t < NPB) fh[t] = 0;
    __syncthreads();

    int b = blockIdx.x;
    int base = boffs[b];
    int cnt = min(bcnt[b], CAPS);
    const uint* rb = gbin + (size_t)base * 8;

    // register-staged sid pass: hist
    int sid[RPT];
#pragma unroll
    for (int c = 0; c < RPT; c++) {
        int i = t + c * TBF;
        sid[c] = -1;
        if (i < cnt) {
            sid[c] = (int)(rb[(size_t)i * 8 + 7] >> 16) & (NPB - 1);
            atomicAdd(&fh[sid[c]], 1);
        }
    }
    __syncthreads();
    if (t < NPB) fstart[t] = fh[t];
    __syncthreads();
    for (int d = 1; d < NPB; d <<= 1) {
        int add = (t < NPB && t >= d) ? fstart[t - d] : 0;
        __syncthreads();
        if (t < NPB) fstart[t] += add;
        __syncthreads();
    }
    if (t < NPB) { int s0 = fstart[t] - fh[t]; fstart[t] = s0; fcur[t] = s0; }
    __syncthreads();
    // placement from registers
#pragma unroll
    for (int c = 0; c < RPT; c++) {
        if (sid[c] >= 0) {
            int p = atomicAdd(&fcur[sid[c]], 1);
            idx[p] = (ushort)(t + c * TBF);
        }
    }
    __syncthreads();

    // ---- two 128-node passes: moments + stats + node MLP ----
    for (int pass = 0; pass < 2; pass++) {
        int l = t >> 2, lq = t & 3;            // 128 nodes x 4 lanes
        int ln = pass * 128 + l;               // local node in bucket
        int s = (b << BSH) + ln;
        int n = fh[ln], start = fstart[ln];

        float s1[4] = {0.f,0.f,0.f,0.f}, s2[4] = {0.f,0.f,0.f,0.f};
        float s3[4] = {0.f,0.f,0.f,0.f}, s4[4] = {0.f,0.f,0.f,0.f};
        if (s < NSs) {
            for (int k = 0; k < n; k++) {
                int ri = idx[start + k];
                uint2 rv = *(const uint2*)(rb + (size_t)ri * 8 + lq * 2);
                union { uint uu[2]; _Float16 h[4]; } up;
                up.uu[0] = rv.x; up.uu[1] = rv.y;
#pragma unroll
                for (int j = 0; j < 4; j++) {
                    float x = (float)up.h[j];   // f==15 slot is sid; excluded at write
                    float x2 = x * x;
                    s1[j] += x;
                    s2[j] = fmaf(x, x, s2[j]);
                    s3[j] = fmaf(x2, x, s3[j]);
                    s4[j] = fmaf(x2, x2, s4[j]);
                }
            }
            float inv = 1.0f / (float)(n > 1 ? n : 1);
#pragma unroll
            for (int j = 0; j < 4; j++) {
                int f = lq * 4 + j;
                if (f < H1) {
                    float a = s1[j] * inv, m2 = s2[j] * inv, m3 = s3[j] * inv, m4 = s4[j] * inv;
                    float a2 = a * a;
                    float var = m2 - a2;
                    float bb = sqrtf(1e-6f + fmaxf(var, 0.0f));
                    float c3 = m3 - 3.0f * a * m2 + 2.0f * a * a2;
                    float c4 = m4 - 4.0f * a * m3 + 6.0f * a2 * m2 - 3.0f * a2 * a2;
                    float ib = 1.0f / bb, ib2 = ib * ib;
                    feat[l][f * 4 + 0] = a;
                    feat[l][f * 4 + 1] = bb;
                    feat[l][f * 4 + 2] = c3 * ib * ib2;
                    feat[l][f * 4 + 3] = c4 * ib2 * ib2;
                }
            }
            if (lq == 0) feat[l][60] = (float)n;
        }
        __syncthreads();

        // node MLP layer 1 (epilogue pattern verified R10)
        for (int id = t; id < 128 * FXS; id += TBF) {
            int g = id / FXS, j = id - g * FXS;
            int ss = (b << BSH) + pass * 128 + g;
            if (ss >= NSs) continue;
            const float* ar = feat[g];
            float acc = sb3[j];
            const float* xr = x_s + (size_t)ss * FXS;
#pragma unroll
            for (int i = 0; i < FXS; i++) acc = fmaf(xr[i], sW3[i * FXS + j], acc);
            acc = fmaf(ar[60], sW3[FXS * FXS + j], acc);
#pragma unroll
            for (int f = 0; f < H1; f++) {
                acc = fmaf(ar[f * 4 + 0], sW3[(11 + f) * FXS + j], acc);
                acc = fmaf(ar[f * 4 + 1], sW3[(26 + f) * FXS + j], acc);
                acc = fmaf(ar[f * 4 + 2], sW3[(41 + f) * FXS + j], acc);
                acc = fmaf(ar[f * 4 + 3], sW3[(56 + f) * FXS + j], acc);
            }
            const float* ur = u + (size_t)batch_s[ss] * FU;
#pragma unroll
            for (int i = 0; i < FU; i++) acc = fmaf(ur[i], sW3[(71 + i) * FXS + j], acc);
            l1s[g][j] = fmaxf(acc, 0.1f * acc);
        }
        __syncthreads();

        // node MLP layer 2 + output
        for (int id = t; id < 128 * FXS; id += TBF) {
            int g = id / FXS, j = id - g * FXS;
            int ss = (b << BSH) + pass * 128 + g;
            if (ss >= NSs) continue;
            float acc = sb4[j];
#pragma unroll
            for (int i = 0; i < FXS; i++) acc = fmaf(l1s[g][i], sW4[i * FXS + j], acc);
            out[(size_t)ss * FXS + j] = acc;
        }
        __syncthreads();   // feat/l1s reused next pass
    }
}

extern "C" void kernel_launch(void* const* d_in, const int* in_sizes, int n_in,
                              void* d_out, int out_size, void* d_ws, size_t ws_size,
                              hipStream_t stream) {
    const float* x_s = (const float*)d_in[0];
    const float* x_t = (const float*)d_in[1];
    const float* ea  = (const float*)d_in[2];
    const float* u   = (const float*)d_in[3];
    const float* W1  = (const float*)d_in[4];
    const float* b1  = (const float*)d_in[5];
    const float* W2  = (const float*)d_in[6];
    const float* b2  = (const float*)d_in[7];
    const float* W3  = (const float*)d_in[8];
    const float* b3  = (const float*)d_in[9];
    const float* W4  = (const float*)d_in[10];
    const float* b4  = (const float*)d_in[11];
    const int* src   = (const int*)d_in[12];
    const int* tgt   = (const int*)d_in[13];
    const int* batch_s = (const int*)d_in[14];

    int NSs = in_sizes[0] / FXS;
    int E   = in_sizes[2] / FE;
    int nbuk = (NSs + NPB - 1) >> BSH;

    auto align_up = [](size_t x) { return (x + 255) & ~(size_t)255; };
    char* w = (char*)d_ws;
    int* bcnt   = (int*)w; w += align_up((size_t)MAXBUK * 4);
    int* boffs  = (int*)w; w += align_up((size_t)MAXBUK * 4);
    int* bcur   = (int*)w; w += align_up((size_t)MAXBUK * 4);
    uint* gbin  = (uint*)w;   // E * 32 bytes

    hipMemsetAsync(bcnt, 0, (size_t)MAXBUK * 4, stream);

    k_bhist<<<512, 256, 0, stream>>>(src, bcnt, E, nbuk);
    k_bscan<<<1, MAXBUK, 0, stream>>>(bcnt, boffs, bcur, nbuk);
    k_mlpbin<<<(E + ABLK - 1) / ABLK, TB1, 0, stream>>>(
        x_t, ea, W1, b1, W2, b2, src, tgt, bcur, gbin, E);
    k_fuse<<<nbuk, TBF, 0, stream>>>(
        x_s, u, W3, b3, W4, b4, batch_s, bcnt, boffs, gbin, (float*)d_out, NSs);
}